// Round 1
// baseline (216.178 us; speedup 1.0000x reference)
//
#include <hip/hip_runtime.h>

// GraphSAGE-style fused gather + weighted-mean + Linear(256->128) + ReLU
// N=100000 nodes, K=16 neighbors, D=128, V=1e6 rows (f32).
//
// Strategy: memory-bound on random row gathers (~870 MB). One wave handles
// M=8 nodes: coalesced float2/lane row gathers, comb vector staged in a
// per-wave LDS slot, then fp32 VALU matmul with W1 streamed from L2
// (amortized 8x) and uniform-addr ds_read_b128 broadcasts of comb.

#define NN 100000
#define KK 16
#define DD 128
#define MM 8           // nodes per wave
#define WAVES_PER_BLOCK 4

__global__ __launch_bounds__(256)
void graphsage_kernel(const int* __restrict__ video_nodes,
                      const int* __restrict__ neighbors,
                      const float* __restrict__ neigh_weights,
                      const float* __restrict__ emb,
                      const float* __restrict__ W1,
                      const float* __restrict__ b1,
                      float* __restrict__ out)
{
    // per-wave private comb slots: 4 waves * 8 nodes * 256 f32 = 32 KB
    __shared__ float comb[WAVES_PER_BLOCK][MM][2 * DD];

    const int lane = threadIdx.x & 63;
    const int wib  = __builtin_amdgcn_readfirstlane(threadIdx.x >> 6);
    const int gwave = blockIdx.x * WAVES_PER_BLOCK + wib;
    const int node0 = gwave * MM;
    if (node0 >= NN) return;   // grid sized exactly; defensive only

    // ---- Phase 1: gather self + weighted-mean neighbors, stash comb in LDS
    #pragma unroll
    for (int m = 0; m < MM; ++m) {
        const int n = node0 + m;
        const int sidx = video_nodes[n];
        const float2 sv =
            *reinterpret_cast<const float2*>(&emb[(size_t)sidx * DD + 2 * lane]);

        float2 acc = make_float2(0.0f, 0.0f);
        float wsum = 0.0f;
        #pragma unroll
        for (int k = 0; k < KK; ++k) {
            const int   idx = neighbors[n * KK + k];
            const float w   = neigh_weights[n * KK + k];
            wsum += w;
            const float2 e =
                *reinterpret_cast<const float2*>(&emb[(size_t)idx * DD + 2 * lane]);
            acc.x = fmaf(w, e.x, acc.x);
            acc.y = fmaf(w, e.y, acc.y);
        }
        const float inv = 1.0f / wsum;

        *reinterpret_cast<float2*>(&comb[wib][m][2 * lane]) = sv;
        *reinterpret_cast<float2*>(&comb[wib][m][DD + 2 * lane]) =
            make_float2(acc.x * inv, acc.y * inv);
    }
    // same-wave LDS produce->consume: compiler orders via lgkmcnt, no barrier.

    // ---- Phase 2: out[n][d] = relu(b1[d] + sum_j comb[n][j] * W1[j][d])
    const float2 bias = *reinterpret_cast<const float2*>(&b1[2 * lane]);
    float2 acc[MM];
    #pragma unroll
    for (int m = 0; m < MM; ++m) acc[m] = bias;

    for (int j4 = 0; j4 < 2 * DD; j4 += 4) {
        float4 cj[MM];
        #pragma unroll
        for (int m = 0; m < MM; ++m)
            cj[m] = *reinterpret_cast<const float4*>(&comb[wib][m][j4]);

        #pragma unroll
        for (int jj = 0; jj < 4; ++jj) {
            const float2 w1v = *reinterpret_cast<const float2*>(
                &W1[(size_t)(j4 + jj) * DD + 2 * lane]);
            #pragma unroll
            for (int m = 0; m < MM; ++m) {
                const float c = (jj == 0) ? cj[m].x
                              : (jj == 1) ? cj[m].y
                              : (jj == 2) ? cj[m].z
                                          : cj[m].w;
                acc[m].x = fmaf(c, w1v.x, acc[m].x);
                acc[m].y = fmaf(c, w1v.y, acc[m].y);
            }
        }
    }

    // ---- Epilogue: ReLU + coalesced store
    #pragma unroll
    for (int m = 0; m < MM; ++m) {
        const int n = node0 + m;
        float2 r;
        r.x = fmaxf(acc[m].x, 0.0f);
        r.y = fmaxf(acc[m].y, 0.0f);
        *reinterpret_cast<float2*>(&out[(size_t)n * DD + 2 * lane]) = r;
    }
}

extern "C" void kernel_launch(void* const* d_in, const int* in_sizes, int n_in,
                              void* d_out, int out_size, void* d_ws, size_t ws_size,
                              hipStream_t stream) {
    const int*   video_nodes   = (const int*)d_in[0];
    const int*   neighbors     = (const int*)d_in[1];
    const float* neigh_weights = (const float*)d_in[2];
    const float* emb           = (const float*)d_in[3];
    const float* W1            = (const float*)d_in[4];
    const float* b1            = (const float*)d_in[5];
    float*       out           = (float*)d_out;

    const int nodes_per_block = WAVES_PER_BLOCK * MM;           // 32
    const int grid = (NN + nodes_per_block - 1) / nodes_per_block; // 3125

    graphsage_kernel<<<grid, 256, 0, stream>>>(
        video_nodes, neighbors, neigh_weights, emb, W1, b1, out);
}

// Round 2
// 174.055 us; speedup vs baseline: 1.2420x; 1.2420x over previous
//
#include <hip/hip_runtime.h>
#include <hip/hip_bf16.h>

// GraphSAGE fused gather + weighted-mean + Linear(256->128) + ReLU
// N=100000, K=16, D=128, V=1e6 rows (f32 table).
//
// Round 2: phase-2 matmul moved to bf16 MFMA.
//  - prep kernel: W1 [256][128] f32 -> W1T [128][256] bf16 in d_ws (64 KB).
//  - main kernel: 16 nodes/wave. Phase 1 gathers rows (coalesced float2/lane,
//    fp32 accumulation), packs comb to bf16 into an XOR-swizzled per-wave LDS
//    slot. Phase 2: D[d][node] = W1T-tile (A) x comb^T-tile (B) via
//    mfma_f32_16x16x32_bf16; epilogue bias+ReLU with contiguous float4 stores.

#define NN 100000
#define KK 16
#define DD 128
#define MM 16          // nodes per wave
#define WPB 4          // waves per block

typedef __attribute__((ext_vector_type(8))) short short8;   // 8 x bf16
typedef __attribute__((ext_vector_type(4))) float f32x4;

// ---- prep: W1T[d][k] = bf16(W1[k][d]) ----
__global__ __launch_bounds__(256)
void prep_w1t_kernel(const float* __restrict__ W1, __hip_bfloat16* __restrict__ W1T)
{
    const int tid = blockIdx.x * blockDim.x + threadIdx.x;  // 32768 threads
    const int d = tid >> 8;      // 0..127
    const int k = tid & 255;     // 0..255
    W1T[d * 256 + k] = __float2bfloat16(W1[k * DD + d]);    // writes coalesced
}

__global__ __launch_bounds__(256, 4)
void graphsage_kernel(const int* __restrict__ video_nodes,
                      const int* __restrict__ neighbors,
                      const float* __restrict__ neigh_weights,
                      const float* __restrict__ emb,
                      const __hip_bfloat16* __restrict__ W1T,
                      const float* __restrict__ b1,
                      float* __restrict__ out)
{
    // per-wave comb slot: [MM nodes][256 k] bf16 = 8 KB; 4 waves -> 32 KB
    __shared__ __hip_bfloat16 comb[WPB][MM][2 * DD];

    const int lane = threadIdx.x & 63;
    const int wib  = __builtin_amdgcn_readfirstlane(threadIdx.x >> 6);
    const int node0 = (blockIdx.x * WPB + wib) * MM;
    if (node0 >= NN) return;

    char* const slot = (char*)&comb[wib][0][0];

    // ---- Phase 1: gather + weighted mean, pack bf16 into swizzled LDS ----
    #pragma unroll 2
    for (int m = 0; m < MM; ++m) {
        const int n = node0 + m;                 // wave-uniform
        const int sidx = video_nodes[n];
        const float2 sv =
            *reinterpret_cast<const float2*>(&emb[(size_t)sidx * DD + 2 * lane]);

        float2 acc = make_float2(0.0f, 0.0f);
        float wsum = 0.0f;
        #pragma unroll
        for (int k = 0; k < KK; ++k) {
            const int   idx = neighbors[n * KK + k];
            const float w   = neigh_weights[n * KK + k];
            wsum += w;
            const float2 e =
                *reinterpret_cast<const float2*>(&emb[(size_t)idx * DD + 2 * lane]);
            acc.x = fmaf(w, e.x, acc.x);
            acc.y = fmaf(w, e.y, acc.y);
        }
        const float inv = 1.0f / wsum;

        // XOR swizzle: flip byte bits 4..6 by (node&7)<<4 (stays in 128B window)
        const unsigned swz = (unsigned)((m & 7) << 4);
        const unsigned sb  = ((unsigned)(m * 512 + 4 * lane)) ^ swz;        // self: k=2*lane
        const unsigned nb  = ((unsigned)(m * 512 + 256 + 4 * lane)) ^ swz;  // neigh: k=128+2*lane

        __hip_bfloat162 sp;
        sp.x = __float2bfloat16(sv.x);
        sp.y = __float2bfloat16(sv.y);
        __hip_bfloat162 ng;
        ng.x = __float2bfloat16(acc.x * inv);
        ng.y = __float2bfloat16(acc.y * inv);
        *reinterpret_cast<__hip_bfloat162*>(slot + sb) = sp;
        *reinterpret_cast<__hip_bfloat162*>(slot + nb) = ng;
    }
    // wave-private slot: same-wave ds_write->ds_read ordered via lgkmcnt,
    // no barrier needed.

    // ---- Phase 2: MFMA.  D[d][node] = sum_k W1T[d][k] * comb[node][k] ----
    const int nodeB  = lane & 15;    // B col / D col
    const int kchunk = lane >> 4;    // 0..3
    const unsigned swzB = (unsigned)((nodeB & 7) << 4);

    // B fragments (comb^T): lane -> comb[nodeB][kt*32 + kchunk*8 + j]
    short8 bfrag[8];
    #pragma unroll
    for (int kt = 0; kt < 8; ++kt) {
        const unsigned byte =
            ((unsigned)(nodeB * 512 + kt * 64 + kchunk * 16)) ^ swzB;
        bfrag[kt] = *reinterpret_cast<const short8*>(slot + byte);
    }

    const int drow = lane & 15;      // A row within d-tile
    #pragma unroll
    for (int dt = 0; dt < 8; ++dt) {
        const int d = dt * 16 + drow;
        f32x4 acc = {0.0f, 0.0f, 0.0f, 0.0f};
        #pragma unroll
        for (int kt = 0; kt < 8; ++kt) {
            const short8 afrag = *reinterpret_cast<const short8*>(
                &W1T[d * 256 + kt * 32 + kchunk * 8]);
            acc = __builtin_amdgcn_mfma_f32_16x16x32_bf16(afrag, bfrag[kt], acc,
                                                          0, 0, 0);
        }
        // D: col = lane&15 = node, row = kchunk*4 + reg = d within tile
        const int node = node0 + (lane & 15);
        const int d0   = dt * 16 + kchunk * 4;
        const float4 bias = *reinterpret_cast<const float4*>(&b1[d0]);
        float4 r;
        r.x = fmaxf(acc[0] + bias.x, 0.0f);
        r.y = fmaxf(acc[1] + bias.y, 0.0f);
        r.z = fmaxf(acc[2] + bias.z, 0.0f);
        r.w = fmaxf(acc[3] + bias.w, 0.0f);
        *reinterpret_cast<float4*>(&out[(size_t)node * DD + d0]) = r;
    }
}

extern "C" void kernel_launch(void* const* d_in, const int* in_sizes, int n_in,
                              void* d_out, int out_size, void* d_ws, size_t ws_size,
                              hipStream_t stream) {
    const int*   video_nodes   = (const int*)d_in[0];
    const int*   neighbors     = (const int*)d_in[1];
    const float* neigh_weights = (const float*)d_in[2];
    const float* emb           = (const float*)d_in[3];
    const float* W1            = (const float*)d_in[4];
    const float* b1            = (const float*)d_in[5];
    float*       out           = (float*)d_out;

    __hip_bfloat16* W1T = (__hip_bfloat16*)d_ws;   // 64 KB (ws is ~2 GB)

    // 32768 elements, one thread each
    prep_w1t_kernel<<<DD * 256 / 256, 256, 0, stream>>>(W1, W1T);

    const int nodes_per_block = WPB * MM;                          // 64
    const int grid = (NN + nodes_per_block - 1) / nodes_per_block; // 1563
    graphsage_kernel<<<grid, 256, 0, stream>>>(
        video_nodes, neighbors, neigh_weights, emb, W1T, b1, out);
}

// Round 3
// 169.031 us; speedup vs baseline: 1.2789x; 1.0297x over previous
//
#include <hip/hip_runtime.h>
#include <hip/hip_bf16.h>

// GraphSAGE fused gather + weighted-mean + Linear(256->128) + ReLU
// N=100000, K=16, D=128, V=1e6 rows (f32 table).
//
// Round 3: paired-row gathers. One global_load_dwordx4 fetches TWO embedding
// rows (lanes 0-31 -> node 2mp, lanes 32-63 -> node 2mp+1; 16 B/lane x 32
// lanes = full 512 B row per half-wave). Halves phase-1 VMEM instruction
// count vs round 2 and doubles bytes-in-flight per instruction. Indices &
// weights are wave-uniform scalar loads + per-half cndmask select. Phase 2
// (bf16 MFMA vs pre-transposed W1T, XOR-swizzled LDS comb) unchanged.

#define NN 100000
#define KK 16
#define DD 128
#define MM 16          // nodes per wave
#define WPB 4          // waves per block

typedef __attribute__((ext_vector_type(8))) short short8;   // 8 x bf16
typedef __attribute__((ext_vector_type(4))) float f32x4;

// ---- prep: W1T[d][k] = bf16(W1[k][d]) ----
__global__ __launch_bounds__(256)
void prep_w1t_kernel(const float* __restrict__ W1, __hip_bfloat16* __restrict__ W1T)
{
    const int tid = blockIdx.x * blockDim.x + threadIdx.x;  // 32768 threads
    const int d = tid >> 8;      // 0..127
    const int k = tid & 255;     // 0..255
    W1T[d * 256 + k] = __float2bfloat16(W1[k * DD + d]);
}

static __device__ __forceinline__ unsigned pk_bf16(float a, float b) {
    __hip_bfloat162 t;
    t.x = __float2bfloat16(a);
    t.y = __float2bfloat16(b);
    return *reinterpret_cast<unsigned*>(&t);
}

__global__ __launch_bounds__(256, 4)
void graphsage_kernel(const int* __restrict__ video_nodes,
                      const int* __restrict__ neighbors,
                      const float* __restrict__ neigh_weights,
                      const float* __restrict__ emb,
                      const __hip_bfloat16* __restrict__ W1T,
                      const float* __restrict__ b1,
                      float* __restrict__ out)
{
    // per-wave comb slot: [MM nodes][256 k] bf16 = 8 KB; 4 waves -> 32 KB
    __shared__ __hip_bfloat16 comb[WPB][MM][2 * DD];

    const int lane = threadIdx.x & 63;
    const int wib  = __builtin_amdgcn_readfirstlane(threadIdx.x >> 6);
    const int node0 = (blockIdx.x * WPB + wib) * MM;
    if (node0 >= NN) return;   // 100000 = 6250 full waves; tail waves exit whole

    char* const slot = (char*)&comb[wib][0][0];
    const char* const embB = (const char*)emb;

    const int half = lane >> 5;               // which node of the pair
    const int c    = lane & 31;               // column group: floats 4c..4c+3
    const unsigned byte_c = 16u * (unsigned)c;

    // ---- Phase 1: paired gathers + weighted mean, pack bf16 into LDS ----
    #pragma unroll 2
    for (int mp = 0; mp < MM / 2; ++mp) {
        const int n0 = node0 + 2 * mp;        // wave-uniform
        const int n1 = n0 + 1;

        // self rows (issued first, consumed last)
        const int s0i = video_nodes[n0];      // scalar
        const int s1i = video_nodes[n1];      // scalar
        const int sidx = half ? s1i : s0i;
        const float4 sv = *reinterpret_cast<const float4*>(
            embB + ((((unsigned)sidx) << 9) + byte_c));

        f32x4 acc = {0.0f, 0.0f, 0.0f, 0.0f};
        float wsum = 0.0f;
        #pragma unroll
        for (int k = 0; k < KK; ++k) {
            const int   i0 = neighbors[n0 * KK + k];        // scalar
            const int   i1 = neighbors[n1 * KK + k];        // scalar
            const float w0 = neigh_weights[n0 * KK + k];    // scalar
            const float w1 = neigh_weights[n1 * KK + k];    // scalar
            const int   rk = half ? i1 : i0;                // cndmask
            const float wk = half ? w1 : w0;                // cndmask
            wsum += wk;
            const float4 e = *reinterpret_cast<const float4*>(
                embB + ((((unsigned)rk) << 9) + byte_c));   // saddr + 32b voff
            acc[0] = fmaf(wk, e.x, acc[0]);
            acc[1] = fmaf(wk, e.y, acc[1]);
            acc[2] = fmaf(wk, e.z, acc[2]);
            acc[3] = fmaf(wk, e.w, acc[3]);
        }
        const float inv = 1.0f / wsum;

        // LDS pack: element j of node's 256-wide comb row lives at byte
        // (node*512 + 2j) ^ ((node&7)<<4).  This lane owns self j=4c..4c+3
        // and neigh j=128+4c..128+4c+3 -> two 8 B writes.
        const int nodel = 2 * mp + half;
        const unsigned swz = (unsigned)((nodel & 7) << 4);
        const unsigned sb = ((unsigned)(nodel * 512) + 8u * c) ^ swz;
        const unsigned nb = ((unsigned)(nodel * 512 + 256) + 8u * c) ^ swz;

        uint2 sU, nU;
        sU.x = pk_bf16(sv.x, sv.y);
        sU.y = pk_bf16(sv.z, sv.w);
        nU.x = pk_bf16(acc[0] * inv, acc[1] * inv);
        nU.y = pk_bf16(acc[2] * inv, acc[3] * inv);
        *reinterpret_cast<uint2*>(slot + sb) = sU;
        *reinterpret_cast<uint2*>(slot + nb) = nU;
    }
    // wave-private slot: same-wave ds_write->ds_read ordered via lgkmcnt.

    // ---- Phase 2: MFMA.  D[d][node] = sum_k W1T[d][k] * comb[node][k] ----
    const int nodeB  = lane & 15;    // B col / D col
    const int kchunk = lane >> 4;    // 0..3
    const unsigned swzB = (unsigned)((nodeB & 7) << 4);

    short8 bfrag[8];
    #pragma unroll
    for (int kt = 0; kt < 8; ++kt) {
        const unsigned byte =
            ((unsigned)(nodeB * 512 + kt * 64 + kchunk * 16)) ^ swzB;
        bfrag[kt] = *reinterpret_cast<const short8*>(slot + byte);
    }

    const int drow = lane & 15;      // A row within d-tile
    #pragma unroll
    for (int dt = 0; dt < 8; ++dt) {
        const int d = dt * 16 + drow;
        f32x4 acc = {0.0f, 0.0f, 0.0f, 0.0f};
        #pragma unroll
        for (int kt = 0; kt < 8; ++kt) {
            const short8 afrag = *reinterpret_cast<const short8*>(
                &W1T[d * 256 + kt * 32 + kchunk * 8]);
            acc = __builtin_amdgcn_mfma_f32_16x16x32_bf16(afrag, bfrag[kt], acc,
                                                          0, 0, 0);
        }
        // D: col = lane&15 = node, row = kchunk*4 + reg = d within tile
        const int node = node0 + (lane & 15);
        const int d0   = dt * 16 + kchunk * 4;
        const float4 bias = *reinterpret_cast<const float4*>(&b1[d0]);
        float4 r;
        r.x = fmaxf(acc[0] + bias.x, 0.0f);
        r.y = fmaxf(acc[1] + bias.y, 0.0f);
        r.z = fmaxf(acc[2] + bias.z, 0.0f);
        r.w = fmaxf(acc[3] + bias.w, 0.0f);
        *reinterpret_cast<float4*>(&out[(size_t)node * DD + d0]) = r;
    }
}

extern "C" void kernel_launch(void* const* d_in, const int* in_sizes, int n_in,
                              void* d_out, int out_size, void* d_ws, size_t ws_size,
                              hipStream_t stream) {
    const int*   video_nodes   = (const int*)d_in[0];
    const int*   neighbors     = (const int*)d_in[1];
    const float* neigh_weights = (const float*)d_in[2];
    const float* emb           = (const float*)d_in[3];
    const float* W1            = (const float*)d_in[4];
    const float* b1            = (const float*)d_in[5];
    float*       out           = (float*)d_out;

    __hip_bfloat16* W1T = (__hip_bfloat16*)d_ws;   // 64 KB

    prep_w1t_kernel<<<DD * 256 / 256, 256, 0, stream>>>(W1, W1T);

    const int nodes_per_block = WPB * MM;                          // 64
    const int grid = (NN + nodes_per_block - 1) / nodes_per_block; // 1563
    graphsage_kernel<<<grid, 256, 0, stream>>>(
        video_nodes, neighbors, neigh_weights, emb, W1T, b1, out);
}